// Round 1
// baseline (577.314 us; speedup 1.0000x reference)
//
#include <hip/hip_runtime.h>
#include <math.h>

#define HIDN 64
#define NCLS_K 32
#define INDIM 256

// ---------------- per-node projections: pa = h.att_w[:64], pb = h.att_w[64:]
__global__ __launch_bounds__(256) void proj_kernel(const float* __restrict__ hid,
    const float* __restrict__ attw, float* __restrict__ pa, float* __restrict__ pb, int n) {
  int wid  = (blockIdx.x * blockDim.x + threadIdx.x) >> 6;
  int lane = threadIdx.x & 63;
  if (wid >= n) return;
  float v = hid[(size_t)wid * HIDN + lane];
  float a = v * attw[lane];
  float b = v * attw[HIDN + lane];
  #pragma unroll
  for (int off = 32; off >= 1; off >>= 1) {
    a += __shfl_xor(a, off, 64);
    b += __shfl_xor(b, off, 64);
  }
  if (lane == 0) { pa[wid] = a; pb[wid] = b; }
}

// ---------------- CSR build
__global__ __launch_bounds__(256) void degree_kernel(const int* __restrict__ src,
                                                     int* __restrict__ cnt, int e) {
  int i = blockIdx.x * blockDim.x + threadIdx.x;
  if (i < e) atomicAdd(&cnt[src[i]], 1);
}

__global__ __launch_bounds__(256) void scan_block(const int* __restrict__ cnt,
    int* __restrict__ rowp, int* __restrict__ blk, int n) {
  __shared__ int sm[256];
  int i = blockIdx.x * 256 + threadIdx.x;
  int v = (i < n) ? cnt[i] : 0;
  sm[threadIdx.x] = v;
  __syncthreads();
  for (int off = 1; off < 256; off <<= 1) {
    int t = (threadIdx.x >= (unsigned)off) ? sm[threadIdx.x - off] : 0;
    __syncthreads();
    sm[threadIdx.x] += t;
    __syncthreads();
  }
  if (i < n) rowp[i] = sm[threadIdx.x] - v;      // exclusive within block
  if (threadIdx.x == 255) blk[blockIdx.x] = sm[255];
}

__global__ __launch_bounds__(512) void scan_spine(int* __restrict__ blk,
    int* __restrict__ rowp, int nblk, int n) {
  __shared__ int sm[512];
  int tid = threadIdx.x;
  int v = (tid < nblk) ? blk[tid] : 0;
  sm[tid] = v;
  __syncthreads();
  for (int off = 1; off < 512; off <<= 1) {
    int t = (tid >= off) ? sm[tid - off] : 0;
    __syncthreads();
    sm[tid] += t;
    __syncthreads();
  }
  if (tid < nblk) blk[tid] = sm[tid] - v;        // exclusive block offsets
  if (tid == 511) rowp[n] = sm[511];             // total == E
}

__global__ __launch_bounds__(256) void scan_add(int* __restrict__ rowp,
    const int* __restrict__ blk, int n) {
  int i = blockIdx.x * blockDim.x + threadIdx.x;
  if (i < n) rowp[i] += blk[i >> 8];
}

__global__ __launch_bounds__(256) void scatter_kernel(const int* __restrict__ src,
    const int* __restrict__ dst, const int* __restrict__ rowp,
    int* __restrict__ cursor, int* __restrict__ dstc, int e) {
  int i = blockIdx.x * blockDim.x + threadIdx.x;
  if (i < e) {
    int s = src[i];
    int pos = rowp[s] + atomicAdd(&cursor[s], 1);
    dstc[pos] = dst[i];
  }
}

// ---------------- per-row (src-segmented) edge softmax, wave per row
__global__ __launch_bounds__(256) void att_softmax(const float* __restrict__ pa,
    const float* __restrict__ pb, const int* __restrict__ dstc,
    const int* __restrict__ rowp, float* __restrict__ attv, int n) {
  int wid  = (blockIdx.x * blockDim.x + threadIdx.x) >> 6;
  int lane = threadIdx.x & 63;
  if (wid >= n) return;
  int start = rowp[wid], end = rowp[wid + 1];
  if (start == end) return;
  float pai = pa[wid];
  float m = -3.0e38f;
  for (int base = start; base < end; base += 64) {
    int e = base + lane;
    float s = -3.0e38f;
    if (e < end) {
      float v = pai + pb[dstc[e]];
      s = v > 0.f ? v : 0.01f * v;        // leaky_relu slope 0.01
      attv[e] = s;
    }
    m = fmaxf(m, s);
  }
  #pragma unroll
  for (int off = 32; off >= 1; off >>= 1) m = fmaxf(m, __shfl_xor(m, off, 64));
  float sum = 0.f;
  for (int base = start; base < end; base += 64) {
    int e = base + lane;
    float ex = 0.f;
    if (e < end) { ex = expf(attv[e] - m); attv[e] = ex; }
    sum += ex;
  }
  #pragma unroll
  for (int off = 32; off >= 1; off >>= 1) sum += __shfl_xor(sum, off, 64);
  float inv = 1.f / sum;
  for (int base = start; base < end; base += 64) {
    int e = base + lane;
    if (e < end) attv[e] *= inv;
  }
}

// ---------------- dense X = H @ W, thread per row, W at wave-uniform addresses
template <int K, int J>
__global__ __launch_bounds__(256) void gemm_rowthread(const float* __restrict__ H,
    const float* __restrict__ W, float* __restrict__ X, int n) {
  int i = blockIdx.x * blockDim.x + threadIdx.x;
  if (i >= n) return;
  float acc[J];
  #pragma unroll
  for (int j = 0; j < J; ++j) acc[j] = 0.f;
  const float* hrow = H + (size_t)i * K;
  #pragma unroll 2
  for (int k = 0; k < K; k += 4) {
    float4 h4 = *reinterpret_cast<const float4*>(hrow + k);
    #pragma unroll
    for (int j = 0; j < J; ++j) {
      acc[j] += h4.x * W[(k + 0) * J + j];
      acc[j] += h4.y * W[(k + 1) * J + j];
      acc[j] += h4.z * W[(k + 2) * J + j];
      acc[j] += h4.w * W[(k + 3) * J + j];
    }
  }
  float* xrow = X + (size_t)i * J;
  #pragma unroll
  for (int j = 0; j < J; j += 4) {
    float4 o = make_float4(acc[j], acc[j + 1], acc[j + 2], acc[j + 3]);
    *reinterpret_cast<float4*>(xrow + j) = o;
  }
}

// ---------------- SpMM + ELU (+ fused log_softmax on final layer), wave per row
template <int J, bool FINAL>
__global__ __launch_bounds__(256) void spmm_elu(const float* __restrict__ X,
    const float* __restrict__ attv, const int* __restrict__ dstc,
    const int* __restrict__ rowp, float* __restrict__ out, int n) {
  int wid  = (blockIdx.x * blockDim.x + threadIdx.x) >> 6;
  int lane = threadIdx.x & 63;
  if (wid >= n) return;
  int start = rowp[wid], end = rowp[wid + 1];
  int col = (J == 64) ? lane : (lane & (J - 1));
  float a0 = 0.f, a1 = 0.f, a2 = 0.f, a3 = 0.f;
  for (int base = start; base < end; base += 64) {
    int e = base + lane;
    float av = 0.f; int dv = 0;
    if (e < end) { av = attv[e]; dv = dstc[e]; }
    int cnt = min(64, end - base);
    int t = 0;
    for (; t + 4 <= cnt; t += 4) {
      float b0 = __shfl(av, t + 0); int d0 = __shfl(dv, t + 0);
      float b1 = __shfl(av, t + 1); int d1 = __shfl(dv, t + 1);
      float b2 = __shfl(av, t + 2); int d2 = __shfl(dv, t + 2);
      float b3 = __shfl(av, t + 3); int d3 = __shfl(dv, t + 3);
      a0 += b0 * X[(size_t)d0 * J + col];
      a1 += b1 * X[(size_t)d1 * J + col];
      a2 += b2 * X[(size_t)d2 * J + col];
      a3 += b3 * X[(size_t)d3 * J + col];
    }
    for (; t < cnt; ++t) {
      float b = __shfl(av, t); int d = __shfl(dv, t);
      a0 += b * X[(size_t)d * J + col];
    }
  }
  float acc = (a0 + a1) + (a2 + a3);
  acc = acc > 0.f ? acc : (expf(acc) - 1.f);     // ELU
  if (!FINAL) {
    out[(size_t)wid * J + lane] = acc;
  } else {
    // log_softmax over the 32 columns (lanes 32..63 mirror 0..31)
    float m = acc;
    #pragma unroll
    for (int off = 16; off >= 1; off >>= 1) m = fmaxf(m, __shfl_xor(m, off, 32));
    float ex = expf(acc - m);
    float s = ex;
    #pragma unroll
    for (int off = 16; off >= 1; off >>= 1) s += __shfl_xor(s, off, 32);
    if (lane < J) out[(size_t)wid * J + lane] = acc - m - logf(s);
  }
}

extern "C" void kernel_launch(void* const* d_in, const int* in_sizes, int n_in,
                              void* d_out, int out_size, void* d_ws, size_t ws_size,
                              hipStream_t stream) {
  const float* features = (const float*)d_in[0];
  const float* hidden   = (const float*)d_in[1];
  const int*   adj      = (const int*)d_in[2];
  const float* W0       = (const float*)d_in[3];
  const float* W1       = (const float*)d_in[4];
  const float* W2       = (const float*)d_in[5];
  const float* attw     = (const float*)d_in[6];
  float* out = (float*)d_out;

  const int N = in_sizes[1] / HIDN;   // 100000
  const int E = in_sizes[2] / 2;      // 1600000
  const int* src = adj;
  const int* dst = adj + E;

  // workspace layout (all segments multiple of 16 elements -> 64B aligned)
  // total: (5N+16 + 512) ints/floats + 2E + 2*N*64 floats  ~= 66.2 MB
  float* pa    = (float*)d_ws;              // N
  float* pb    = pa + N;                    // N
  int*   rowp  = (int*)(pb + N);            // N+16
  int*   cnt   = rowp + (N + 16);           // N
  int*   cursor= cnt + N;                   // N
  int*   blks  = cursor + N;                // 512
  int*   dstc  = blks + 512;                // E
  float* attv  = (float*)(dstc + E);        // E
  float* X     = attv + E;                  // N*64
  float* H     = X + (size_t)N * HIDN;      // N*64

  (void)hipMemsetAsync(cnt,    0, (size_t)N * sizeof(int), stream);
  (void)hipMemsetAsync(cursor, 0, (size_t)N * sizeof(int), stream);

  dim3 blk(256);
  const int gridWave = (N + 3) / 4;         // 4 waves (rows) per 256-thread block
  const int gridE    = (E + 255) / 256;
  const int gridRow  = (N + 255) / 256;
  const int nblk     = (N + 255) / 256;

  proj_kernel<<<gridWave, blk, 0, stream>>>(hidden, attw, pa, pb, N);
  degree_kernel<<<gridE, blk, 0, stream>>>(src, cnt, E);
  scan_block<<<nblk, blk, 0, stream>>>(cnt, rowp, blks, N);
  scan_spine<<<1, 512, 0, stream>>>(blks, rowp, nblk, N);
  scan_add<<<nblk, blk, 0, stream>>>(rowp, blks, N);
  scatter_kernel<<<gridE, blk, 0, stream>>>(src, dst, rowp, cursor, dstc, E);
  att_softmax<<<gridWave, blk, 0, stream>>>(pa, pb, dstc, rowp, attv, N);

  gemm_rowthread<INDIM, HIDN><<<gridRow, blk, 0, stream>>>(features, W0, X, N);
  spmm_elu<HIDN, false><<<gridWave, blk, 0, stream>>>(X, attv, dstc, rowp, H, N);
  gemm_rowthread<HIDN, HIDN><<<gridRow, blk, 0, stream>>>(H, W1, X, N);
  spmm_elu<HIDN, false><<<gridWave, blk, 0, stream>>>(X, attv, dstc, rowp, H, N);
  gemm_rowthread<HIDN, NCLS_K><<<gridRow, blk, 0, stream>>>(H, W2, X, N);
  spmm_elu<NCLS_K, true><<<gridWave, blk, 0, stream>>>(X, attv, dstc, rowp, out, N);
}